// Round 4
// baseline (243.683 us; speedup 1.0000x reference)
//
#include <hip/hip_runtime.h>

typedef unsigned short u16;
typedef unsigned int u32;
typedef __bf16 bf16x2 __attribute__((ext_vector_type(2)));
typedef __bf16 bf16x4 __attribute__((ext_vector_type(4)));
typedef __bf16 bf16x8 __attribute__((ext_vector_type(8)));
typedef float  f32x4  __attribute__((ext_vector_type(4)));
typedef float  f32x16 __attribute__((ext_vector_type(16)));
typedef u32    u32x4  __attribute__((ext_vector_type(4)));

#define MFMA16(a, b, c) __builtin_amdgcn_mfma_f32_16x16x32_bf16((a), (b), (c), 0, 0, 0)
#define MFMA32(a, b, c) __builtin_amdgcn_mfma_f32_32x32x16_bf16((a), (b), (c), 0, 0, 0)

static __device__ __forceinline__ u32 pkbf(float a, float b) {
    bf16x2 t;
    t[0] = (__bf16)a;
    t[1] = (__bf16)b;
    return __builtin_bit_cast(u32, t);
}

// ---------------------------------------------------------------------------
// Geometry: N=2, L=2048, E=1024, H=16, D=64.
// R11: BARRIER-FREE flash. Key insight: the K/V MFMA A-fragments are
// wave-invariant (depend on lane only), so LDS staging only deduped loads
// across the 4 waves — which the 32KB/CU L1 does for free. K/V frags now
// load directly from global (L1/L2-served); NO __syncthreads in the whole
// kernel (epilogue Pw region is wave-private). Waves decorrelate -> the
// QK/softmax/PV phase-lockstep (the measured 31% dual-pipe idle) is gone.
// + T1 XCD swizzle: 128 consecutive blocks (4 nh) per XCD -> 2MB K/V
// working set fits the 4MB per-XCD L2. LDS 36.9->18.4 KB.
// prep/out_gemm untouched (attribution).
// ---------------------------------------------------------------------------

// Kernel 1: fused {Wo f32->bf16 convert | shared projection}.
// Blocks 0..3071: y = x @ Wv^T + bv for values/keys/query.
// Blocks 3072..4095: Wo convert.
// Q,K stored [nh][l][d] bf16; V stored transposed [nh][d][l] bf16.
// Q additionally scaled by log2(e)/sqrt(1024) (folded softmax scale).
__global__ __launch_bounds__(256) void prep_kernel(
    const float* __restrict__ values, const float* __restrict__ keys,
    const float* __restrict__ query,  const float* __restrict__ Wv,
    const float* __restrict__ bv,     const float* __restrict__ Wo,
    u16* __restrict__ Qb, u16* __restrict__ Kb, u16* __restrict__ VTb,
    u16* __restrict__ Wob) {
    const int b = blockIdx.x;
    const int t = b >> 10;
    if (t == 3) {  // Wo convert
        const int i = ((b - 3072) * 256 + threadIdx.x) * 4;
        float4 v = *(const float4*)&Wo[i];
        bf16x4 o = { (__bf16)v.x, (__bf16)v.y, (__bf16)v.z, (__bf16)v.w };
        *(bf16x4*)&Wob[i] = o;
        return;
    }
    __shared__ __align__(16) u16 Wvs[64 * 72];
    __shared__ __align__(16) u16 Xs[64 * 72];
    const int lt = b & 31, h = (b >> 5) & 15, n = (b >> 9) & 1;
    const int nh = n * 16 + h, l0 = lt * 64;
    const int tid = threadIdx.x, wave = tid >> 6, lane = tid & 63;
    const int quad = lane >> 4, l16 = lane & 15;
    const float* xin = (t == 0) ? values : (t == 1 ? keys : query);

#pragma unroll
    for (int j = 0; j < 4; ++j) {
        const int chunk = tid + 256 * j, r = chunk >> 4, c = (chunk & 15) * 4;
        float4 w = *(const float4*)&Wv[r * 64 + c];
        bf16x4 wb = { (__bf16)w.x, (__bf16)w.y, (__bf16)w.z, (__bf16)w.w };
        *(bf16x4*)&Wvs[r * 72 + c] = wb;
        float4 x = *(const float4*)&xin[(size_t)(n * 2048 + l0 + r) * 1024 + h * 64 + c];
        bf16x4 xb = { (__bf16)x.x, (__bf16)x.y, (__bf16)x.z, (__bf16)x.w };
        *(bf16x4*)&Xs[r * 72 + c] = xb;
    }
    __syncthreads();

    bf16x8 wf[4][2], xf[2];
#pragma unroll
    for (int f = 0; f < 4; ++f)
#pragma unroll
        for (int ks = 0; ks < 2; ++ks)
            wf[f][ks] = *(const bf16x8*)&Wvs[(f * 16 + l16) * 72 + ks * 32 + quad * 8];
#pragma unroll
    for (int ks = 0; ks < 2; ++ks)
        xf[ks] = *(const bf16x8*)&Xs[(wave * 16 + l16) * 72 + ks * 32 + quad * 8];

    f32x4 acc[4];
#pragma unroll
    for (int i = 0; i < 4; ++i) acc[i] = (f32x4){0.f, 0.f, 0.f, 0.f};

    if (t == 0) {  // V: y = x·Wv^T
#pragma unroll
        for (int nf = 0; nf < 4; ++nf) {
            acc[nf] = MFMA16(xf[0], wf[nf][0], acc[nf]);
            acc[nf] = MFMA16(xf[1], wf[nf][1], acc[nf]);
        }
    } else {       // Q/K: y^T = Wv·x^T
#pragma unroll
        for (int mf = 0; mf < 4; ++mf) {
            acc[mf] = MFMA16(wf[mf][0], xf[0], acc[mf]);
            acc[mf] = MFMA16(wf[mf][1], xf[1], acc[mf]);
        }
    }
    __syncthreads();

    const float scale = (t == 2) ? 0.04508422f : 1.0f;  // log2(e)/sqrt(1024)
    if (t == 0) {
#pragma unroll
        for (int nf = 0; nf < 4; ++nf) {
            const float bias = bv[nf * 16 + l16];
            bf16x4 o = { (__bf16)(acc[nf][0] + bias), (__bf16)(acc[nf][1] + bias),
                         (__bf16)(acc[nf][2] + bias), (__bf16)(acc[nf][3] + bias) };
            *(bf16x4*)&Xs[(nf * 16 + l16) * 72 + wave * 16 + quad * 4] = o;
        }
    } else {
#pragma unroll
        for (int mf = 0; mf < 4; ++mf) {
            bf16x4 o = { (__bf16)((acc[mf][0] + bv[mf * 16 + quad * 4 + 0]) * scale),
                         (__bf16)((acc[mf][1] + bv[mf * 16 + quad * 4 + 1]) * scale),
                         (__bf16)((acc[mf][2] + bv[mf * 16 + quad * 4 + 2]) * scale),
                         (__bf16)((acc[mf][3] + bv[mf * 16 + quad * 4 + 3]) * scale) };
            *(bf16x4*)&Xs[(wave * 16 + l16) * 72 + mf * 16 + quad * 4] = o;
        }
    }
    __syncthreads();

    u16* dst = (t == 0) ? VTb : (t == 1 ? Kb : Qb);
#pragma unroll
    for (int j = 0; j < 2; ++j) {
        const int chunk = tid + 256 * j, r = chunk >> 3, c = (chunk & 7) * 8;
        const size_t off = (t == 0) ? (size_t)(nh * 64 + r) * 2048 + l0 + c
                                    : (size_t)(nh * 2048 + l0 + r) * 64 + c;
        *(int4*)&dst[off] = *(const int4*)&Xs[r * 72 + c];
    }
}

// Kernel 2: attention partials, 32x32x16 MFMA, split-K x2, NO BARRIERS.
// Block = 256 thr (4 waves x 32 q); grid = 32 nh x 16 slab x 2 ks, XCD-
// swizzled so XCD p runs original block IDs p*128..p*128+127 (4 nh/XCD).
// Per kt: load K frags (global, L1-shared across waves) -> QK^T t2=0 ->
// softmax0 -> issue V dt=0 frag loads -> QK^T t2=1 -> softmax1 -> issue V
// dt=1 loads -> PV dt=0 -> PV dt=1. In-register P^T via permlane32_swap.
// S-tile: lane (l32,h) reg r=4a+bb holds S[key=bb+8a+4h+32t2][q=l32].
__global__ __launch_bounds__(256, 4) void flash_kernel(
    const u16* __restrict__ Qb, const u16* __restrict__ Kb,
    const u16* __restrict__ VTb, u16* __restrict__ Op,
    float* __restrict__ Lp) {
    __shared__ __align__(16) u16 Ps[4][32 * 72];  // epilogue transpose only
    const int L = blockIdx.x;
    const int b = (L & 7) * 128 + (L >> 3);  // XCD-grouping swizzle (bijective)
    const int nh = b >> 5, qsl = (b >> 1) & 15, ks = b & 1;
    const int tid = threadIdx.x, wave = tid >> 6, lane = tid & 63;
    const int l32 = lane & 31, half = lane >> 5;
    const int q0 = qsl * 128 + wave * 32;
    const int s4 = (b >> 1) * 4 + wave;  // (nh*16+qsl)*4 + wave
    u16* Pw = &Ps[wave][0];

    // Q B-frags direct from global: B[kd=kg*16+half*8+j][q=l32].
    const u16* Qg = Qb + ((size_t)nh * 2048 + q0) * 64;
    bf16x8 qf[4];
#pragma unroll
    for (int kg = 0; kg < 4; ++kg)
        qf[kg] = *(const bf16x8*)&Qg[l32 * 64 + kg * 16 + half * 8];

    f32x16 Oacc[2];
#pragma unroll
    for (int dt = 0; dt < 2; ++dt)
#pragma unroll
        for (int r = 0; r < 16; ++r) Oacc[dt][r] = 0.f;
    float lsum = 0.f;

    // Per-lane element bases. K frag (t2,kg) @ Kl[(kt*64+t2*32)*64 + kg*16];
    // V frag (dt,kk) @ Vl[dt*65536 + kt*64 + kk*16].
    const u16* Kl = Kb + (size_t)nh * 131072 + (size_t)(ks * 1024 + l32) * 64 + half * 8;
    const u16* Vl = VTb + (size_t)nh * 131072 + (size_t)l32 * 2048 + ks * 1024 + half * 8;

    for (int kt = 0; kt < 16; ++kt) {
        const int kb = kt * 64;
        bf16x8 bp[4];
        bf16x8 vf0[4], vf1[4];
#pragma unroll
        for (int t2 = 0; t2 < 2; ++t2) {
            bf16x8 kf[4];
#pragma unroll
            for (int kg = 0; kg < 4; ++kg)
                kf[kg] = *(const bf16x8*)&Kl[(size_t)(kb + t2 * 32) * 64 + kg * 16];
            f32x16 s;
#pragma unroll
            for (int r = 0; r < 16; ++r) s[r] = 0.f;
            __builtin_amdgcn_s_setprio(1);
#pragma unroll
            for (int kg = 0; kg < 4; ++kg)
                s = MFMA32(kf[kg], qf[kg], s);
            __builtin_amdgcn_s_setprio(0);
            // exp2, per-lane partial row sums, pack to bf16 words W[a][0..1].
            u32 W[4][2];
#pragma unroll
            for (int a = 0; a < 4; ++a) {
                const float p0 = __builtin_amdgcn_exp2f(s[4 * a + 0]);
                const float p1 = __builtin_amdgcn_exp2f(s[4 * a + 1]);
                const float p2 = __builtin_amdgcn_exp2f(s[4 * a + 2]);
                const float p3 = __builtin_amdgcn_exp2f(s[4 * a + 3]);
                lsum += (p0 + p1) + (p2 + p3);
                W[a][0] = pkbf(p0, p1);
                W[a][1] = pkbf(p2, p3);
            }
            // Redistribute across the half-pair: one swap fills two words.
#pragma unroll
            for (int g = 0; g < 2; ++g) {
                u32 x0 = W[2 * g][0], y0 = W[2 * g + 1][0];
                u32 x1 = W[2 * g][1], y1 = W[2 * g + 1][1];
                asm("v_permlane32_swap_b32 %0, %1" : "+v"(x0), "+v"(y0));
                asm("v_permlane32_swap_b32 %0, %1" : "+v"(x1), "+v"(y1));
                u32x4 w = { x0, x1, y0, y1 };
                bp[2 * t2 + g] = __builtin_bit_cast(bf16x8, w);
            }
            // Issue V frag loads for dt=t2 now: latency hides under the
            // remaining QK/softmax (dt=0) or PV dt=0 (dt=1).
            if (t2 == 0) {
#pragma unroll
                for (int kk = 0; kk < 4; ++kk)
                    vf0[kk] = *(const bf16x8*)&Vl[kb + kk * 16];
            } else {
#pragma unroll
                for (int kk = 0; kk < 4; ++kk)
                    vf1[kk] = *(const bf16x8*)&Vl[65536 + kb + kk * 16];
            }
        }

        // O^T += V^T·P^T : A[m=d=dt*32+l32][k=key], B[k=key][q=l32] (in reg)
        __builtin_amdgcn_s_setprio(1);
#pragma unroll
        for (int kk = 0; kk < 4; ++kk)
            Oacc[0] = MFMA32(vf0[kk], bp[kk], Oacc[0]);
#pragma unroll
        for (int kk = 0; kk < 4; ++kk)
            Oacc[1] = MFMA32(vf1[kk], bp[kk], Oacc[1]);
        __builtin_amdgcn_s_setprio(0);
    }

    // Fold the two key-halves of this lane's partial row sum -> l(q) per ks.
    const float lq = lsum + __shfl_xor(lsum, 32);
    if (half == 0)
        Lp[((size_t)s4 * 2 + ks) * 32 + l32] = lq;

    // Epilogue: transpose O^T (C layout: col=q=l32, row=d=(r&3)+8*(r>>2)+
    // 4*half+32*dt) into O[q][d] via the wave-private Ps region (no barrier
    // needed), then store bf16 partials in final AO layout (coalesced b128).
#pragma unroll
    for (int dt = 0; dt < 2; ++dt)
#pragma unroll
        for (int a = 0; a < 4; ++a) {
            bf16x4 o = { (__bf16)Oacc[dt][4 * a + 0], (__bf16)Oacc[dt][4 * a + 1],
                         (__bf16)Oacc[dt][4 * a + 2], (__bf16)Oacc[dt][4 * a + 3] };
            *(bf16x4*)&Pw[l32 * 72 + dt * 32 + a * 8 + half * 4] = o;
        }
    u16* Ob = Op + (size_t)ks * 4194304 +
              ((size_t)(nh >> 4) * 2048 + q0) * 1024 + (nh & 15) * 64;
#pragma unroll
    for (int j = 0; j < 4; ++j) {
        const int chunk = lane + 64 * j, r = chunk >> 3, c = (chunk & 7) * 8;
        *(int4*)&Ob[(size_t)r * 1024 + c] = *(const int4*)&Pw[r * 72 + c];
    }
}

// Kernel 3: out = ((O1+O2)*inv_l)(4096x1024 bf16) @ Wo^T + bo, f32 out.
// Combine fused into A-staging (h = kt constant per K-iter; l(n,h,q) is 2
// L2-resident f32 loads per staged row). Double-buffered As/Bs, ONE
// barrier per kt. Reg-prefetch + setprio.
// 512-thr blocks, 128x64 tile, 8 waves each one 32x32 subtile (MFMA32).
__global__ __launch_bounds__(512) void out_gemm_kernel(
    const u16* __restrict__ Op, const float* __restrict__ Lp,
    const u16* __restrict__ Bw, const float* __restrict__ bo,
    float* __restrict__ out) {
    __shared__ __align__(16) u16 As[2][128 * 72];
    __shared__ __align__(16) u16 Bs[2][64 * 72];
    const int b = blockIdx.x, rt = b >> 4, ct = b & 15;
    const int row0 = rt * 128, col0 = ct * 64;
    const int tid = threadIdx.x, wave = tid >> 6, lane = tid & 63;
    const int l32 = lane & 31, half = lane >> 5;
    const int wr = wave & 3, wc = wave >> 2;

    // Staging geometry: A rows rA0 (0..63) and rA1=rA0+64; B row rB.
    const int rA0 = tid >> 3, cA = (tid & 7) * 8;
    const int rA1 = rA0 + 64;
    const int rB = rA0, cB = cA;

    // Per-row Lp element index (s4*64 + q); +4096 per K-iter folds h=kt.
    int lpidx[2];
#pragma unroll
    for (int j = 0; j < 2; ++j) {
        const int row = row0 + rA0 + j * 64;
        const int n = row >> 11, qsl = (row >> 7) & 15, w = (row >> 5) & 3,
                  q = row & 31;
        lpidx[j] = (((n * 256 + qsl) << 2) + w) * 64 + q;
    }

    f32x16 acc;
#pragma unroll
    for (int r = 0; r < 16; ++r) acc[r] = 0.f;

    // Prologue: issue tile 0 loads.
    bf16x8 a1r[2], a2r[2];
    int4 br;
    float lr[2][2];
    {
        const size_t off0 = (size_t)(row0 + rA0) * 1024 + cA;
        const size_t off1 = (size_t)(row0 + rA1) * 1024 + cA;
        a1r[0] = *(const bf16x8*)&Op[off0];
        a2r[0] = *(const bf16x8*)&Op[4194304 + off0];
        a1r[1] = *(const bf16x8*)&Op[off1];
        a2r[1] = *(const bf16x8*)&Op[4194304 + off1];
        br = *(const int4*)&Bw[(size_t)(col0 + rB) * 1024 + cB];
        lr[0][0] = Lp[lpidx[0]];
        lr[0][1] = Lp[lpidx[0] + 32];
        lr[1][0] = Lp[lpidx[1]];
        lr[1][1] = Lp[lpidx[1] + 32];
    }

    for (int kt = 0; kt < 16; ++kt) {
        u16* Ac = As[kt & 1];
        u16* Bc = Bs[kt & 1];
#pragma unroll
        for (int j = 0; j < 2; ++j) {
            const float inv = 1.0f / (lr[j][0] + lr[j][1]);
            bf16x8 o;
#pragma unroll
            for (int i = 0; i < 8; ++i)
                o[i] = (__bf16)(((float)a1r[j][i] + (float)a2r[j][i]) * inv);
            *(bf16x8*)&Ac[(rA0 + j * 64) * 72 + cA] = o;
        }
        *(int4*)&Bc[rB * 72 + cB] = br;
        if (kt < 15) {  // issue next tile; hides under MFMA phase
            const int kn = (kt + 1) * 64;
            const size_t off0 = (size_t)(row0 + rA0) * 1024 + kn + cA;
            const size_t off1 = (size_t)(row0 + rA1) * 1024 + kn + cA;
            a1r[0] = *(const bf16x8*)&Op[off0];
            a2r[0] = *(const bf16x8*)&Op[4194304 + off0];
            a1r[1] = *(const bf16x8*)&Op[off1];
            a2r[1] = *(const bf16x8*)&Op[4194304 + off1];
            br = *(const int4*)&Bw[(size_t)(col0 + rB) * 1024 + kn + cB];
            const int li0 = lpidx[0] + (kt + 1) * 4096;
            const int li1 = lpidx[1] + (kt + 1) * 4096;
            lr[0][0] = Lp[li0];
            lr[0][1] = Lp[li0 + 32];
            lr[1][0] = Lp[li1];
            lr[1][1] = Lp[li1 + 32];
        }
        __syncthreads();  // buf[kt&1] staged; prior buf reads drained
        __builtin_amdgcn_s_setprio(1);
#pragma unroll
        for (int kg = 0; kg < 4; ++kg) {
            bf16x8 af = *(const bf16x8*)&Ac[(wr * 32 + l32) * 72 + kg * 16 + half * 8];
            bf16x8 bf = *(const bf16x8*)&Bc[(wc * 32 + l32) * 72 + kg * 16 + half * 8];
            acc = MFMA32(af, bf, acc);
        }
        __builtin_amdgcn_s_setprio(0);
    }

    // C layout: col = l32 (local), row = (r&3)+8*(r>>2)+4*half (local).
    const int col = col0 + wc * 32 + l32;
    const float bias = bo[col];
#pragma unroll
    for (int r = 0; r < 16; ++r) {
        const int row = row0 + wr * 32 + (r & 3) + 8 * (r >> 2) + 4 * half;
        out[(size_t)row * 1024 + col] = acc[r] + bias;
    }
}

extern "C" void kernel_launch(void* const* d_in, const int* in_sizes, int n_in,
                              void* d_out, int out_size, void* d_ws, size_t ws_size,
                              hipStream_t stream) {
    (void)in_sizes; (void)n_in; (void)out_size; (void)ws_size;
    const float* values = (const float*)d_in[0];
    const float* keys   = (const float*)d_in[1];
    const float* query  = (const float*)d_in[2];
    const float* Wv     = (const float*)d_in[3];
    const float* bv     = (const float*)d_in[4];
    const float* Wo     = (const float*)d_in[5];
    const float* bo     = (const float*)d_in[6];

    char* ws = (char*)d_ws;
    u16*   Qb  = (u16*)(ws);                     // [32][2048][64] bf16, 8 MB
    u16*   Kb  = (u16*)(ws + (8ull  << 20));     // [32][2048][64] bf16, 8 MB
    u16*   VTb = (u16*)(ws + (16ull << 20));     // [32][64][2048] bf16, 8 MB
    u16*   Wob = (u16*)(ws + (32ull << 20));     // [1024][1024]  bf16, 2 MB
    u16*   Op  = (u16*)(ws + (34ull << 20));     // 2 x [4096][1024] bf16, 16 MB
    float* Lp  = (float*)(ws + (50ull << 20));   // [2048][2][32] f32, 512 KB

    prep_kernel<<<4096, 256, 0, stream>>>(values, keys, query, Wv, bv, Wo,
                                          Qb, Kb, VTb, Wob);
    flash_kernel<<<1024, 256, 0, stream>>>(Qb, Kb, VTb, Op, Lp);
    out_gemm_kernel<<<512, 512, 0, stream>>>(Op, Lp, Wob, bo, (float*)d_out);
}

// Round 5
// 164.450 us; speedup vs baseline: 1.4818x; 1.4818x over previous
//
#include <hip/hip_runtime.h>

typedef unsigned short u16;
typedef unsigned int u32;
typedef __bf16 bf16x2 __attribute__((ext_vector_type(2)));
typedef __bf16 bf16x4 __attribute__((ext_vector_type(4)));
typedef __bf16 bf16x8 __attribute__((ext_vector_type(8)));
typedef float  f32x4  __attribute__((ext_vector_type(4)));
typedef float  f32x16 __attribute__((ext_vector_type(16)));
typedef u32    u32x4  __attribute__((ext_vector_type(4)));

#define MFMA16(a, b, c) __builtin_amdgcn_mfma_f32_16x16x32_bf16((a), (b), (c), 0, 0, 0)
#define MFMA32(a, b, c) __builtin_amdgcn_mfma_f32_32x32x16_bf16((a), (b), (c), 0, 0, 0)

static __device__ __forceinline__ u32 pkbf(float a, float b) {
    bf16x2 t;
    t[0] = (__bf16)a;
    t[1] = (__bf16)b;
    return __builtin_bit_cast(u32, t);
}

// ---------------------------------------------------------------------------
// Geometry: N=2, L=2048, E=1024, H=16, D=64.  LDS tiles: pitch 72 bf16.
// R12: flash reverted verbatim to R10 (43.2 us measured; R11's direct-from-
// global fragment loads were uncoalesced + un-prefetched -> 125 us, lesson:
// LDS staging IS the coalescing transform here). out_gemm: (a) v_rcp_f32
// for the combine divide (bf16 data, 22-bit rcp is plenty); (b) XCD swizzle
// so each XCD owns 4 complete rt-slabs -> A-slab becomes L2-resident
// instead of being fetched into all 8 XCDs' L2s. prep untouched.
// ---------------------------------------------------------------------------

// Kernel 1: fused {Wo f32->bf16 convert | shared projection}.
// Blocks 0..3071: y = x @ Wv^T + bv for values/keys/query.
// Blocks 3072..4095: Wo convert.
// Q,K stored [nh][l][d] bf16; V stored transposed [nh][d][l] bf16.
// Q additionally scaled by log2(e)/sqrt(1024) (folded softmax scale).
__global__ __launch_bounds__(256) void prep_kernel(
    const float* __restrict__ values, const float* __restrict__ keys,
    const float* __restrict__ query,  const float* __restrict__ Wv,
    const float* __restrict__ bv,     const float* __restrict__ Wo,
    u16* __restrict__ Qb, u16* __restrict__ Kb, u16* __restrict__ VTb,
    u16* __restrict__ Wob) {
    const int b = blockIdx.x;
    const int t = b >> 10;
    if (t == 3) {  // Wo convert
        const int i = ((b - 3072) * 256 + threadIdx.x) * 4;
        float4 v = *(const float4*)&Wo[i];
        bf16x4 o = { (__bf16)v.x, (__bf16)v.y, (__bf16)v.z, (__bf16)v.w };
        *(bf16x4*)&Wob[i] = o;
        return;
    }
    __shared__ __align__(16) u16 Wvs[64 * 72];
    __shared__ __align__(16) u16 Xs[64 * 72];
    const int lt = b & 31, h = (b >> 5) & 15, n = (b >> 9) & 1;
    const int nh = n * 16 + h, l0 = lt * 64;
    const int tid = threadIdx.x, wave = tid >> 6, lane = tid & 63;
    const int quad = lane >> 4, l16 = lane & 15;
    const float* xin = (t == 0) ? values : (t == 1 ? keys : query);

#pragma unroll
    for (int j = 0; j < 4; ++j) {
        const int chunk = tid + 256 * j, r = chunk >> 4, c = (chunk & 15) * 4;
        float4 w = *(const float4*)&Wv[r * 64 + c];
        bf16x4 wb = { (__bf16)w.x, (__bf16)w.y, (__bf16)w.z, (__bf16)w.w };
        *(bf16x4*)&Wvs[r * 72 + c] = wb;
        float4 x = *(const float4*)&xin[(size_t)(n * 2048 + l0 + r) * 1024 + h * 64 + c];
        bf16x4 xb = { (__bf16)x.x, (__bf16)x.y, (__bf16)x.z, (__bf16)x.w };
        *(bf16x4*)&Xs[r * 72 + c] = xb;
    }
    __syncthreads();

    bf16x8 wf[4][2], xf[2];
#pragma unroll
    for (int f = 0; f < 4; ++f)
#pragma unroll
        for (int ks = 0; ks < 2; ++ks)
            wf[f][ks] = *(const bf16x8*)&Wvs[(f * 16 + l16) * 72 + ks * 32 + quad * 8];
#pragma unroll
    for (int ks = 0; ks < 2; ++ks)
        xf[ks] = *(const bf16x8*)&Xs[(wave * 16 + l16) * 72 + ks * 32 + quad * 8];

    f32x4 acc[4];
#pragma unroll
    for (int i = 0; i < 4; ++i) acc[i] = (f32x4){0.f, 0.f, 0.f, 0.f};

    if (t == 0) {  // V: y = x·Wv^T
#pragma unroll
        for (int nf = 0; nf < 4; ++nf) {
            acc[nf] = MFMA16(xf[0], wf[nf][0], acc[nf]);
            acc[nf] = MFMA16(xf[1], wf[nf][1], acc[nf]);
        }
    } else {       // Q/K: y^T = Wv·x^T
#pragma unroll
        for (int mf = 0; mf < 4; ++mf) {
            acc[mf] = MFMA16(wf[mf][0], xf[0], acc[mf]);
            acc[mf] = MFMA16(wf[mf][1], xf[1], acc[mf]);
        }
    }
    __syncthreads();

    const float scale = (t == 2) ? 0.04508422f : 1.0f;  // log2(e)/sqrt(1024)
    if (t == 0) {
#pragma unroll
        for (int nf = 0; nf < 4; ++nf) {
            const float bias = bv[nf * 16 + l16];
            bf16x4 o = { (__bf16)(acc[nf][0] + bias), (__bf16)(acc[nf][1] + bias),
                         (__bf16)(acc[nf][2] + bias), (__bf16)(acc[nf][3] + bias) };
            *(bf16x4*)&Xs[(nf * 16 + l16) * 72 + wave * 16 + quad * 4] = o;
        }
    } else {
#pragma unroll
        for (int mf = 0; mf < 4; ++mf) {
            bf16x4 o = { (__bf16)((acc[mf][0] + bv[mf * 16 + quad * 4 + 0]) * scale),
                         (__bf16)((acc[mf][1] + bv[mf * 16 + quad * 4 + 1]) * scale),
                         (__bf16)((acc[mf][2] + bv[mf * 16 + quad * 4 + 2]) * scale),
                         (__bf16)((acc[mf][3] + bv[mf * 16 + quad * 4 + 3]) * scale) };
            *(bf16x4*)&Xs[(wave * 16 + l16) * 72 + mf * 16 + quad * 4] = o;
        }
    }
    __syncthreads();

    u16* dst = (t == 0) ? VTb : (t == 1 ? Kb : Qb);
#pragma unroll
    for (int j = 0; j < 2; ++j) {
        const int chunk = tid + 256 * j, r = chunk >> 3, c = (chunk & 7) * 8;
        const size_t off = (t == 0) ? (size_t)(nh * 64 + r) * 2048 + l0 + c
                                    : (size_t)(nh * 2048 + l0 + r) * 64 + c;
        *(int4*)&dst[off] = *(const int4*)&Xs[r * 72 + c];
    }
}

// Kernel 2: attention partials with 32x32x16 MFMA + split-K x2.
// Block = 256 thr (4 waves x 32 q = 128-q slab); grid = 32 nh x 16 slab x 2 ks.
// R10 K-loop (verbatim revert): double-buffered Ks/Vs, ONE barrier per kt.
// Iter kt writes buf[kt&1] (regs loaded last iter), prefetches kt+1 to regs,
// barriers, computes from buf[kt&1].
// S-tile: lane (l32,h) reg r=4a+b holds S[key=b+8a+4h+32t2][q=l32].
// PV B-frag via permlane32_swap.
__global__ __launch_bounds__(256, 4) void flash_kernel(
    const u16* __restrict__ Qb, const u16* __restrict__ Kb,
    const u16* __restrict__ VTb, u16* __restrict__ Op,
    float* __restrict__ Lp) {
    __shared__ __align__(16) u16 Ks[2][64 * 72];
    __shared__ __align__(16) u16 Vs[2][64 * 72];
    const int b = blockIdx.x;
    const int nh = b >> 5, qsl = (b >> 1) & 15, ks = b & 1;
    const int tid = threadIdx.x, wave = tid >> 6, lane = tid & 63;
    const int l32 = lane & 31, half = lane >> 5;
    const int q0 = qsl * 128 + wave * 32;
    const int s4 = (b >> 1) * 4 + wave;  // (nh*16+qsl)*4 + wave

    // Q B-frags direct from global: B[kd=kg*16+half*8+j][q=l32].
    const u16* Qg = Qb + ((size_t)nh * 2048 + q0) * 64;
    bf16x8 qf[4];
#pragma unroll
    for (int kg = 0; kg < 4; ++kg)
        qf[kg] = *(const bf16x8*)&Qg[l32 * 64 + kg * 16 + half * 8];

    f32x16 Oacc[2];
#pragma unroll
    for (int dt = 0; dt < 2; ++dt)
#pragma unroll
        for (int r = 0; r < 16; ++r) Oacc[dt][r] = 0.f;
    float lsum = 0.f;

    const u16* Kg = Kb + (size_t)nh * 2048 * 64;
    const u16* Vg = VTb + (size_t)nh * 64 * 2048;

    // Staging geometry: thread covers rows r0 (0..31) and r1=r0+32, col c0.
    const int r0 = tid >> 3, c0 = (tid & 7) * 8;
    const int r1 = r0 + 32;

    // Prologue: issue tile 0 loads into regs.
    int4 kr0, kr1, vr0, vr1;
    {
        const int k0 = ks * 1024;
        kr0 = *(const int4*)&Kg[(size_t)(k0 + r0) * 64 + c0];
        kr1 = *(const int4*)&Kg[(size_t)(k0 + r1) * 64 + c0];
        vr0 = *(const int4*)&Vg[(size_t)r0 * 2048 + k0 + c0];
        vr1 = *(const int4*)&Vg[(size_t)r1 * 2048 + k0 + c0];
    }

    for (int kt = 0; kt < 16; ++kt) {
        u16* Kc = Ks[kt & 1];
        u16* Vc = Vs[kt & 1];
        *(int4*)&Kc[r0 * 72 + c0] = kr0;
        *(int4*)&Kc[r1 * 72 + c0] = kr1;
        *(int4*)&Vc[r0 * 72 + c0] = vr0;
        *(int4*)&Vc[r1 * 72 + c0] = vr1;
        if (kt < 15) {  // issue next tile; latency hides under compute below
            const int kn = ks * 1024 + (kt + 1) * 64;
            kr0 = *(const int4*)&Kg[(size_t)(kn + r0) * 64 + c0];
            kr1 = *(const int4*)&Kg[(size_t)(kn + r1) * 64 + c0];
            vr0 = *(const int4*)&Vg[(size_t)r0 * 2048 + kn + c0];
            vr1 = *(const int4*)&Vg[(size_t)r1 * 2048 + kn + c0];
        }
        __syncthreads();  // buf[kt&1] staged; prior buf reads drained

        bf16x8 bp[4];
        // Two 32-key S^T tiles: s = K(32xd64) · Q^T(d64 x 32q)
#pragma unroll
        for (int t2 = 0; t2 < 2; ++t2) {
            f32x16 s;
#pragma unroll
            for (int r = 0; r < 16; ++r) s[r] = 0.f;
            __builtin_amdgcn_s_setprio(1);
#pragma unroll
            for (int kg = 0; kg < 4; ++kg) {
                bf16x8 ak = *(const bf16x8*)&Kc[(t2 * 32 + l32) * 72 + kg * 16 + half * 8];
                s = MFMA32(ak, qf[kg], s);
            }
            __builtin_amdgcn_s_setprio(0);
            // exp2, per-lane partial row sums, pack to bf16 words W[a][0..1].
            u32 W[4][2];
#pragma unroll
            for (int a = 0; a < 4; ++a) {
                const float p0 = __builtin_amdgcn_exp2f(s[4 * a + 0]);
                const float p1 = __builtin_amdgcn_exp2f(s[4 * a + 1]);
                const float p2 = __builtin_amdgcn_exp2f(s[4 * a + 2]);
                const float p3 = __builtin_amdgcn_exp2f(s[4 * a + 3]);
                lsum += (p0 + p1) + (p2 + p3);
                W[a][0] = pkbf(p0, p1);
                W[a][1] = pkbf(p2, p3);
            }
            // Redistribute across the half-pair: one swap fills two words.
#pragma unroll
            for (int g = 0; g < 2; ++g) {
                u32 x0 = W[2 * g][0], y0 = W[2 * g + 1][0];
                u32 x1 = W[2 * g][1], y1 = W[2 * g + 1][1];
                asm("v_permlane32_swap_b32 %0, %1" : "+v"(x0), "+v"(y0));
                asm("v_permlane32_swap_b32 %0, %1" : "+v"(x1), "+v"(y1));
                u32x4 w = { x0, x1, y0, y1 };
                bp[2 * t2 + g] = __builtin_bit_cast(bf16x8, w);
            }
        }

        // O^T += V^T·P^T : A[m=d=dt*32+l32][k=key], B[k=key][q=l32] (in reg)
        __builtin_amdgcn_s_setprio(1);
#pragma unroll
        for (int kk = 0; kk < 4; ++kk) {
#pragma unroll
            for (int dt = 0; dt < 2; ++dt) {
                bf16x8 av = *(const bf16x8*)&Vc[(dt * 32 + l32) * 72 + kk * 16 + half * 8];
                Oacc[dt] = MFMA32(av, bp[kk], Oacc[dt]);
            }
        }
        __builtin_amdgcn_s_setprio(0);
    }

    // Fold the two key-halves of this lane's partial row sum -> l(q) per ks.
    const float lq = lsum + __shfl_xor(lsum, 32);
    if (half == 0)
        Lp[((size_t)s4 * 2 + ks) * 32 + l32] = lq;

    // Epilogue: transpose O^T (C layout: col=q=l32, row=d=(r&3)+8*(r>>2)+
    // 4*half+32*dt) into O[q][d] via a wave-private 32x72 region carved out
    // of the (now dead) Ks buffers, then store bf16 partials in final AO
    // layout (coalesced b128).
    __syncthreads();  // all waves done with Ks/Vs
    u16* Pw = &Ks[0][0] + wave * 2304;
#pragma unroll
    for (int dt = 0; dt < 2; ++dt)
#pragma unroll
        for (int a = 0; a < 4; ++a) {
            bf16x4 o = { (__bf16)Oacc[dt][4 * a + 0], (__bf16)Oacc[dt][4 * a + 1],
                         (__bf16)Oacc[dt][4 * a + 2], (__bf16)Oacc[dt][4 * a + 3] };
            *(bf16x4*)&Pw[l32 * 72 + dt * 32 + a * 8 + half * 4] = o;
        }
    u16* Ob = Op + (size_t)ks * 4194304 +
              ((size_t)(nh >> 4) * 2048 + q0) * 1024 + (nh & 15) * 64;
#pragma unroll
    for (int j = 0; j < 4; ++j) {
        const int chunk = lane + 64 * j, r = chunk >> 3, c = (chunk & 7) * 8;
        *(int4*)&Ob[(size_t)r * 1024 + c] = *(const int4*)&Pw[r * 72 + c];
    }
}

// Kernel 3: out = ((O1+O2)*inv_l)(4096x1024 bf16) @ Wo^T + bo, f32 out.
// Combine fused into A-staging (h = kt constant per K-iter; l(n,h,q) is 2
// L2-resident f32 loads per staged row). Double-buffered As/Bs, ONE barrier
// per kt. Reg-prefetch + setprio.
// R12: (a) v_rcp_f32 for inv (saves ~10-inst exact-div sequence x32/thread;
// bf16 data only needs 8 mantissa bits); (b) XCD swizzle: XCD p runs
// original blocks p*64..p*64+63 = 4 complete rt-slabs -> A-slab read into
// ONE XCD's L2 instead of all 8.
// 512-thr blocks, 128x64 tile, 8 waves each one 32x32 subtile (MFMA32).
__global__ __launch_bounds__(512) void out_gemm_kernel(
    const u16* __restrict__ Op, const float* __restrict__ Lp,
    const u16* __restrict__ Bw, const float* __restrict__ bo,
    float* __restrict__ out) {
    __shared__ __align__(16) u16 As[2][128 * 72];
    __shared__ __align__(16) u16 Bs[2][64 * 72];
    const int L = blockIdx.x;
    const int b = (L & 7) * 64 + (L >> 3);  // XCD-grouping swizzle (bijective)
    const int rt = b >> 4, ct = b & 15;
    const int row0 = rt * 128, col0 = ct * 64;
    const int tid = threadIdx.x, wave = tid >> 6, lane = tid & 63;
    const int l32 = lane & 31, half = lane >> 5;
    const int wr = wave & 3, wc = wave >> 2;

    // Staging geometry: A rows rA0 (0..63) and rA1=rA0+64; B row rB.
    const int rA0 = tid >> 3, cA = (tid & 7) * 8;
    const int rA1 = rA0 + 64;
    const int rB = rA0, cB = cA;

    // Per-row Lp element index (s4*64 + q); +4096 per K-iter folds h=kt.
    int lpidx[2];
#pragma unroll
    for (int j = 0; j < 2; ++j) {
        const int row = row0 + rA0 + j * 64;
        const int n = row >> 11, qsl = (row >> 7) & 15, w = (row >> 5) & 3,
                  q = row & 31;
        lpidx[j] = (((n * 256 + qsl) << 2) + w) * 64 + q;
    }

    f32x16 acc;
#pragma unroll
    for (int r = 0; r < 16; ++r) acc[r] = 0.f;

    // Prologue: issue tile 0 loads.
    bf16x8 a1r[2], a2r[2];
    int4 br;
    float lr[2][2];
    {
        const size_t off0 = (size_t)(row0 + rA0) * 1024 + cA;
        const size_t off1 = (size_t)(row0 + rA1) * 1024 + cA;
        a1r[0] = *(const bf16x8*)&Op[off0];
        a2r[0] = *(const bf16x8*)&Op[4194304 + off0];
        a1r[1] = *(const bf16x8*)&Op[off1];
        a2r[1] = *(const bf16x8*)&Op[4194304 + off1];
        br = *(const int4*)&Bw[(size_t)(col0 + rB) * 1024 + cB];
        lr[0][0] = Lp[lpidx[0]];
        lr[0][1] = Lp[lpidx[0] + 32];
        lr[1][0] = Lp[lpidx[1]];
        lr[1][1] = Lp[lpidx[1] + 32];
    }

    for (int kt = 0; kt < 16; ++kt) {
        u16* Ac = As[kt & 1];
        u16* Bc = Bs[kt & 1];
#pragma unroll
        for (int j = 0; j < 2; ++j) {
            const float inv = __builtin_amdgcn_rcpf(lr[j][0] + lr[j][1]);
            bf16x8 o;
#pragma unroll
            for (int i = 0; i < 8; ++i)
                o[i] = (__bf16)(((float)a1r[j][i] + (float)a2r[j][i]) * inv);
            *(bf16x8*)&Ac[(rA0 + j * 64) * 72 + cA] = o;
        }
        *(int4*)&Bc[rB * 72 + cB] = br;
        if (kt < 15) {  // issue next tile; hides under MFMA phase
            const int kn = (kt + 1) * 64;
            const size_t off0 = (size_t)(row0 + rA0) * 1024 + kn + cA;
            const size_t off1 = (size_t)(row0 + rA1) * 1024 + kn + cA;
            a1r[0] = *(const bf16x8*)&Op[off0];
            a2r[0] = *(const bf16x8*)&Op[4194304 + off0];
            a1r[1] = *(const bf16x8*)&Op[off1];
            a2r[1] = *(const bf16x8*)&Op[4194304 + off1];
            br = *(const int4*)&Bw[(size_t)(col0 + rB) * 1024 + kn + cB];
            const int li0 = lpidx[0] + (kt + 1) * 4096;
            const int li1 = lpidx[1] + (kt + 1) * 4096;
            lr[0][0] = Lp[li0];
            lr[0][1] = Lp[li0 + 32];
            lr[1][0] = Lp[li1];
            lr[1][1] = Lp[li1 + 32];
        }
        __syncthreads();  // buf[kt&1] staged; prior buf reads drained
        __builtin_amdgcn_s_setprio(1);
#pragma unroll
        for (int kg = 0; kg < 4; ++kg) {
            bf16x8 af = *(const bf16x8*)&Ac[(wr * 32 + l32) * 72 + kg * 16 + half * 8];
            bf16x8 bf = *(const bf16x8*)&Bc[(wc * 32 + l32) * 72 + kg * 16 + half * 8];
            acc = MFMA32(af, bf, acc);
        }
        __builtin_amdgcn_s_setprio(0);
    }

    // C layout: col = l32 (local), row = (r&3)+8*(r>>2)+4*half (local).
    const int col = col0 + wc * 32 + l32;
    const float bias = bo[col];
#pragma unroll
    for (int r = 0; r < 16; ++r) {
        const int row = row0 + wr * 32 + (r & 3) + 8 * (r >> 2) + 4 * half;
        out[(size_t)row * 1024 + col] = acc[r] + bias;
    }
}

extern "C" void kernel_launch(void* const* d_in, const int* in_sizes, int n_in,
                              void* d_out, int out_size, void* d_ws, size_t ws_size,
                              hipStream_t stream) {
    (void)in_sizes; (void)n_in; (void)out_size; (void)ws_size;
    const float* values = (const float*)d_in[0];
    const float* keys   = (const float*)d_in[1];
    const float* query  = (const float*)d_in[2];
    const float* Wv     = (const float*)d_in[3];
    const float* bv     = (const float*)d_in[4];
    const float* Wo     = (const float*)d_in[5];
    const float* bo     = (const float*)d_in[6];

    char* ws = (char*)d_ws;
    u16*   Qb  = (u16*)(ws);                     // [32][2048][64] bf16, 8 MB
    u16*   Kb  = (u16*)(ws + (8ull  << 20));     // [32][2048][64] bf16, 8 MB
    u16*   VTb = (u16*)(ws + (16ull << 20));     // [32][64][2048] bf16, 8 MB
    u16*   Wob = (u16*)(ws + (32ull << 20));     // [1024][1024]  bf16, 2 MB
    u16*   Op  = (u16*)(ws + (34ull << 20));     // 2 x [4096][1024] bf16, 16 MB
    float* Lp  = (float*)(ws + (50ull << 20));   // [2048][2][32] f32, 512 KB

    prep_kernel<<<4096, 256, 0, stream>>>(values, keys, query, Wv, bv, Wo,
                                          Qb, Kb, VTb, Wob);
    flash_kernel<<<1024, 256, 0, stream>>>(Qb, Kb, VTb, Op, Lp);
    out_gemm_kernel<<<512, 512, 0, stream>>>(Op, Lp, Wob, bo, (float*)d_out);
}